// Round 7
// baseline (584.495 us; speedup 1.0000x reference)
//
#include <hip/hip_runtime.h>
#include <math.h>

#define NN 100000
#define NE 1600000
#define NBLK_SCAN 391   // ceil(NN/256)

__device__ __forceinline__ float lrelu(float x) { return x > 0.f ? x : 0.2f * x; }

// ---- init: zero degree / cursor ---------------------------------------
__global__ __launch_bounds__(256) void k_init(int* __restrict__ deg, int* __restrict__ cursor) {
    int i = blockIdx.x * 256 + threadIdx.x;
    if (i < NN) { deg[i] = 0; cursor[i] = 0; }
}

// ---- CSR build: histogram, 3-kernel scan, fill ------------------------
// 2 edges per thread (NE even, grid exact: 3125*256*2 = 1.6M)
__global__ __launch_bounds__(256) void k_deg(const int* __restrict__ dst, int* __restrict__ deg) {
    int e = (blockIdx.x * 256 + threadIdx.x) * 2;
    int2 d2 = *(const int2*)(dst + e);
    atomicAdd(&deg[d2.x], 1);
    atomicAdd(&deg[d2.y], 1);
}

__global__ __launch_bounds__(256) void k_scan1(const int* __restrict__ deg,
                                               int* __restrict__ row_ptr, int* __restrict__ bsum) {
    __shared__ int sm[256];
    int t = threadIdx.x, i = blockIdx.x * 256 + t;
    int v = (i < NN) ? deg[i] : 0;
    sm[t] = v; __syncthreads();
#pragma unroll
    for (int off = 1; off < 256; off <<= 1) {
        int u = (t >= off) ? sm[t - off] : 0;
        __syncthreads();
        sm[t] += u;
        __syncthreads();
    }
    int incl = sm[t];
    if (i < NN) row_ptr[i] = incl - v;           // block-local exclusive
    if (t == 255) bsum[blockIdx.x] = incl;       // block total
}

__global__ __launch_bounds__(512) void k_scan2(int* __restrict__ bsum) {
    __shared__ int sm[512];
    int t = threadIdx.x;
    int v = (t < NBLK_SCAN) ? bsum[t] : 0;
    sm[t] = v; __syncthreads();
#pragma unroll
    for (int off = 1; off < 512; off <<= 1) {
        int u = (t >= off) ? sm[t - off] : 0;
        __syncthreads();
        sm[t] += u;
        __syncthreads();
    }
    if (t < NBLK_SCAN) bsum[t] = sm[t] - v;      // exclusive block prefix
}

__global__ __launch_bounds__(256) void k_scan3(int* __restrict__ row_ptr, const int* __restrict__ bsum) {
    int i = blockIdx.x * 256 + threadIdx.x;
    if (i < NN) row_ptr[i] += bsum[i >> 8];
    if (i == 0) row_ptr[NN] = NE;
}

// packed[i] = (src_node, ew_bits); 2 edges per thread
__global__ __launch_bounds__(256) void k_fill(const int* __restrict__ src, const int* __restrict__ dst,
                                              const float* __restrict__ ew,
                                              const int* __restrict__ row_ptr, int* __restrict__ cursor,
                                              int2* __restrict__ packed) {
    int e = (blockIdx.x * 256 + threadIdx.x) * 2;
    int2 s2 = *(const int2*)(src + e);
    int2 d2 = *(const int2*)(dst + e);
    float2 w2 = *(const float2*)(ew + e);
    int pos = atomicAdd(&cursor[d2.x], 1);
    packed[row_ptr[d2.x] + pos] = make_int2(s2.x, __float_as_int(w2.x));
    pos = atomicAdd(&cursor[d2.y], 1);
    packed[row_ptr[d2.y] + pos] = make_int2(s2.y, __float_as_int(w2.y));
}

// ---- GEMM1 + fused layer-1 attention logits ---------------------------
// h1[N,128] = x[N,128] @ W1[128,128].  Each block computes a 64x64 tile;
// col-block 0 holds heads {0,1}, col-block 1 holds heads {2,3}, so the
// per-(node,head) attention dots reduce fully inside the block via shfl.
__global__ __launch_bounds__(256) void k_gemm1(const float* __restrict__ x,
                                               const float* __restrict__ W,
                                               const float* __restrict__ asrc,
                                               const float* __restrict__ adst,
                                               float* __restrict__ h1,
                                               float* __restrict__ as1,
                                               float* __restrict__ ad1) {
    __shared__ float xs[128][64];   // xs[k][row]
    __shared__ float ws[128][64];   // ws[k][col]
    const int row0 = blockIdx.x * 64;
    const int col0 = blockIdx.y * 64;
    const int t = threadIdx.x;

    {   // x tile (zero-padded past NN)
        int row = t & 63;
        int grow = row0 + row;
        bool ok = grow < NN;
#pragma unroll
        for (int i = 0; i < 8; i++) {
            int kq = (t >> 6) + i * 4;
            float4 v = ok ? *(const float4*)(x + (size_t)grow * 128 + kq * 4)
                          : make_float4(0.f, 0.f, 0.f, 0.f);
            xs[kq * 4 + 0][row] = v.x;
            xs[kq * 4 + 1][row] = v.y;
            xs[kq * 4 + 2][row] = v.z;
            xs[kq * 4 + 3][row] = v.w;
        }
    }
    {   // W tile
#pragma unroll
        for (int i = 0; i < 8; i++) {
            int lin = t + i * 256;
            int kk = lin >> 4;
            int cq = lin & 15;
            float4 v = *(const float4*)(W + (size_t)kk * 128 + col0 + cq * 4);
            *(float4*)&ws[kk][cq * 4] = v;
        }
    }
    __syncthreads();

    const int tx = t & 15, ty = t >> 4;     // thread = rows ty*4..+3, cols tx*4..+3
    float acc[4][4] = {};
#pragma unroll 4
    for (int k = 0; k < 128; k++) {
        float4 a4 = *(const float4*)&xs[k][ty * 4];
        float4 b4 = *(const float4*)&ws[k][tx * 4];
        float a[4] = {a4.x, a4.y, a4.z, a4.w};
        float b[4] = {b4.x, b4.y, b4.z, b4.w};
#pragma unroll
        for (int i = 0; i < 4; i++)
#pragma unroll
            for (int j = 0; j < 4; j++)
                acc[i][j] = fmaf(a[i], b[j], acc[i][j]);
    }

    // store h1 tile
#pragma unroll
    for (int i = 0; i < 4; i++) {
        int r = row0 + ty * 4 + i;
        if (r < NN) {
            float4 v = make_float4(acc[i][0], acc[i][1], acc[i][2], acc[i][3]);
            *(float4*)(h1 + (size_t)r * 128 + col0 + tx * 4) = v;
        }
    }

    // fused attention logits: head = col0/32 + tx/8; this thread's 4 cols
    // are (tx&7)*4..+3 within the head; reduce over the 8-lane tx group.
    const int head = (col0 >> 5) + (tx >> 3);
    const float4 avs = *(const float4*)(asrc + head * 32 + (tx & 7) * 4);
    const float4 avd = *(const float4*)(adst + head * 32 + (tx & 7) * 4);
#pragma unroll
    for (int i = 0; i < 4; i++) {
        float ps = acc[i][0] * avs.x + acc[i][1] * avs.y + acc[i][2] * avs.z + acc[i][3] * avs.w;
        float pd = acc[i][0] * avd.x + acc[i][1] * avd.y + acc[i][2] * avd.z + acc[i][3] * avd.w;
        ps += __shfl_xor(ps, 1); ps += __shfl_xor(ps, 2); ps += __shfl_xor(ps, 4);
        pd += __shfl_xor(pd, 1); pd += __shfl_xor(pd, 2); pd += __shfl_xor(pd, 4);
        int r = row0 + ty * 4 + i;
        if ((tx & 7) == 0 && r < NN) {
            as1[(size_t)r * 4 + head] = ps;
            ad1[(size_t)r * 4 + head] = pd;
        }
    }
}

// ---- layer1: online softmax + gather, wave/node, ring-pipelined -------
// Half-wave `half` processes edges i0, i0+2, ...; lane owns features
// fl*4..fl*4+3 (fl = lane&31, float4 = 16B/lane).  Ring pipeline:
// packed loaded 3 iterations ahead, as1/h1 gathers issued 2 ahead —
// decouples the packed->gather dependent chain from the loop period.
// Halves flash-combine via shfl_xor(32).
__global__ __launch_bounds__(256) void k_msg1(const int* __restrict__ row_ptr,
                                              const int2* __restrict__ packed,
                                              const float* __restrict__ as1,
                                              const float* __restrict__ ad1,
                                              const float* __restrict__ h1,
                                              const float* __restrict__ b1,
                                              float* __restrict__ h2) {
    int gw = (blockIdx.x * 256 + threadIdx.x) >> 6;   // node id
    if (gw >= NN) return;
    const int lane = threadIdx.x & 63;
    const int half = lane >> 5;
    const int fl = lane & 31;
    const int h = fl >> 3;                            // head of this float4
    const float adv = ad1[(size_t)gw * 4 + h];
    const int beg = row_ptr[gw], end = row_ptr[gw + 1];
    const int i0 = beg + half;
    const int cnt = (i0 < end) ? ((end - i0 + 1) >> 1) : 0;

    float m = -INFINITY, den = 0.f;
    float4 acc = make_float4(0.f, 0.f, 0.f, 0.f);

    int2 p0 = make_int2(0, 0), p1 = p0, p2 = p0;
    float av0 = 0.f, av1 = 0.f;
    float4 hv0 = acc, hv1 = acc;
    if (cnt > 0) p0 = packed[i0];
    if (cnt > 1) p1 = packed[i0 + 2];
    if (cnt > 2) p2 = packed[i0 + 4];
    if (cnt > 0) { av0 = as1[(size_t)p0.x * 4 + h];
                   hv0 = *(const float4*)(h1 + (size_t)p0.x * 128 + fl * 4); }
    if (cnt > 1) { av1 = as1[(size_t)p1.x * 4 + h];
                   hv1 = *(const float4*)(h1 + (size_t)p1.x * 128 + fl * 4); }

    for (int k = 0; k < cnt; k++) {
        int2 p3 = make_int2(0, 0);
        if (k + 3 < cnt) p3 = packed[i0 + 2 * (k + 3)];   // packed: 3 ahead
        float av2 = 0.f; float4 hv2 = make_float4(0.f, 0.f, 0.f, 0.f);
        if (k + 2 < cnt) {                                // gathers: 2 ahead
            av2 = as1[(size_t)p2.x * 4 + h];
            hv2 = *(const float4*)(h1 + (size_t)p2.x * 128 + fl * 4);
        }
        // compute edge k (loads issued 2 iterations ago -> ready)
        float el = lrelu(av0 + adv);
        float mn = fmaxf(m, el);
        float s = __expf(m - mn);                         // ==0 on first edge
        float ex = __expf(el - mn);
        den = den * s + ex;
        float cw = ex * __int_as_float(p0.y);
        acc.x = acc.x * s + hv0.x * cw;
        acc.y = acc.y * s + hv0.y * cw;
        acc.z = acc.z * s + hv0.z * cw;
        acc.w = acc.w * s + hv0.w * cw;
        m = mn;
        // ring shift
        p0 = p1; p1 = p2; p2 = p3;
        av0 = av1; hv0 = hv1;
        av1 = av2; hv1 = hv2;
    }
    // flash-combine the two halves (same fl <-> same features/head)
    float M = fmaxf(m, __shfl_xor(m, 32));
    float sc = (m > -INFINITY) ? __expf(m - M) : 0.f;     // guard exp(-inf - -inf)
    den *= sc; acc.x *= sc; acc.y *= sc; acc.z *= sc; acc.w *= sc;
    den   += __shfl_xor(den, 32);
    acc.x += __shfl_xor(acc.x, 32);
    acc.y += __shfl_xor(acc.y, 32);
    acc.z += __shfl_xor(acc.z, 32);
    acc.w += __shfl_xor(acc.w, 32);
    if (half == 0) {
        float rden = 1.f / (den + 1e-16f);
        float4 bv = *(const float4*)(b1 + fl * 4);
        float4 v;
        v.x = fmaxf(acc.x * rden + bv.x, 0.f);
        v.y = fmaxf(acc.y * rden + bv.y, 0.f);
        v.z = fmaxf(acc.z * rden + bv.z, 0.f);
        v.w = fmaxf(acc.w * rden + bv.w, 0.f);
        *(float4*)(h2 + (size_t)gw * 128 + fl * 4) = v;
    }
}

// ---- GEMM2 + fused layer-2 attention logits ---------------------------
__global__ __launch_bounds__(256) void k_gemm2(const float* __restrict__ h2,
                                               const float* __restrict__ W2,
                                               const float* __restrict__ asrc,
                                               const float* __restrict__ adst,
                                               float* __restrict__ g2,
                                               float* __restrict__ as2,
                                               float* __restrict__ ad2) {
    __shared__ float xs[128][64];
    __shared__ float ws2[128 * 40];
    const int row0 = blockIdx.x * 64;
    const int t = threadIdx.x;
    {
        int row = t & 63;
        int grow = row0 + row;
        bool ok = grow < NN;
#pragma unroll
        for (int i = 0; i < 8; i++) {
            int kq = (t >> 6) + i * 4;
            float4 v = ok ? *(const float4*)(h2 + (size_t)grow * 128 + kq * 4)
                          : make_float4(0.f, 0.f, 0.f, 0.f);
            xs[kq * 4 + 0][row] = v.x;
            xs[kq * 4 + 1][row] = v.y;
            xs[kq * 4 + 2][row] = v.z;
            xs[kq * 4 + 3][row] = v.w;
        }
    }
    {
#pragma unroll
        for (int i = 0; i < 5; i++) {
            int lin = t + i * 256;
            *(float4*)&ws2[lin * 4] = *(const float4*)(W2 + lin * 4);
        }
    }
    __syncthreads();
    const int g = t & 3, r = t >> 2;          // 64 rows x 4 col-groups of 10
    float acc[10] = {};
#pragma unroll 4
    for (int k = 0; k < 128; k++) {
        float a = xs[k][r];
        const float* wb = &ws2[k * 40 + g * 10];
#pragma unroll
        for (int j = 0; j < 10; j++) acc[j] = fmaf(a, wb[j], acc[j]);
    }
    int grow = row0 + r;
    if (grow < NN) {
#pragma unroll
        for (int j = 0; j < 10; j++) g2[(size_t)grow * 40 + g * 10 + j] = acc[j];
    }
    // fused attention dots, reduce over the 4-lane g group
    float ps = 0.f, pd = 0.f;
#pragma unroll
    for (int j = 0; j < 10; j++) {
        ps = fmaf(acc[j], asrc[g * 10 + j], ps);
        pd = fmaf(acc[j], adst[g * 10 + j], pd);
    }
    ps += __shfl_xor(ps, 1); ps += __shfl_xor(ps, 2);
    pd += __shfl_xor(pd, 1); pd += __shfl_xor(pd, 2);
    if (g == 0 && grow < NN) { as2[grow] = ps; ad2[grow] = pd; }
}

// ---- layer2: online softmax + gather, wave/node, ring-pipelined -------
// fl = lane&31 owns features fl*2, fl*2+1 (active fl<20, float2 = 8B).
__global__ __launch_bounds__(256) void k_msg2(const int* __restrict__ row_ptr,
                                              const int2* __restrict__ packed,
                                              const float* __restrict__ as2,
                                              const float* __restrict__ ad2,
                                              const float* __restrict__ g2,
                                              const float* __restrict__ b2,
                                              float* __restrict__ out) {
    int gw = (blockIdx.x * 256 + threadIdx.x) >> 6;
    if (gw >= NN) return;
    const int lane = threadIdx.x & 63;
    const int half = lane >> 5;
    const int fl = lane & 31;
    const bool act = fl < 20;
    const float adv = ad2[gw];
    const int beg = row_ptr[gw], end = row_ptr[gw + 1];
    const int i0 = beg + half;
    const int cnt = (i0 < end) ? ((end - i0 + 1) >> 1) : 0;

    float m = -INFINITY, den = 0.f;
    float2 acc = make_float2(0.f, 0.f);

    int2 p0 = make_int2(0, 0), p1 = p0, p2 = p0;
    float av0 = 0.f, av1 = 0.f;
    float2 gv0 = acc, gv1 = acc;
    if (cnt > 0) p0 = packed[i0];
    if (cnt > 1) p1 = packed[i0 + 2];
    if (cnt > 2) p2 = packed[i0 + 4];
    if (cnt > 0) { av0 = as2[p0.x];
                   if (act) gv0 = *(const float2*)(g2 + (size_t)p0.x * 40 + fl * 2); }
    if (cnt > 1) { av1 = as2[p1.x];
                   if (act) gv1 = *(const float2*)(g2 + (size_t)p1.x * 40 + fl * 2); }

    for (int k = 0; k < cnt; k++) {
        int2 p3 = make_int2(0, 0);
        if (k + 3 < cnt) p3 = packed[i0 + 2 * (k + 3)];
        float av2 = 0.f; float2 gv2 = make_float2(0.f, 0.f);
        if (k + 2 < cnt) {
            av2 = as2[p2.x];
            if (act) gv2 = *(const float2*)(g2 + (size_t)p2.x * 40 + fl * 2);
        }
        float el = lrelu(av0 + adv);
        float mn = fmaxf(m, el);
        float s = __expf(m - mn);
        float ex = __expf(el - mn);
        den = den * s + ex;
        float cw = ex * __int_as_float(p0.y);
        acc.x = acc.x * s + gv0.x * cw;
        acc.y = acc.y * s + gv0.y * cw;
        m = mn;
        p0 = p1; p1 = p2; p2 = p3;
        av0 = av1; gv0 = gv1;
        av1 = av2; gv1 = gv2;
    }
    float M = fmaxf(m, __shfl_xor(m, 32));
    float sc = (m > -INFINITY) ? __expf(m - M) : 0.f;
    den *= sc; acc.x *= sc; acc.y *= sc;
    den   += __shfl_xor(den, 32);
    acc.x += __shfl_xor(acc.x, 32);
    acc.y += __shfl_xor(acc.y, 32);
    if (half == 0 && act) {
        float rden = 1.f / (den + 1e-16f);
        float2 bv = *(const float2*)(b2 + fl * 2);
        *(float2*)(out + (size_t)gw * 40 + fl * 2) =
            make_float2(acc.x * rden + bv.x, acc.y * rden + bv.y);
    }
}

// ---- host launcher ----------------------------------------------------
extern "C" void kernel_launch(void* const* d_in, const int* in_sizes, int n_in,
                              void* d_out, int out_size, void* d_ws, size_t ws_size,
                              hipStream_t stream) {
    const float* x     = (const float*)d_in[0];
    const int*   ei    = (const int*)d_in[1];
    const float* ew    = (const float*)d_in[2];
    const float* W1    = (const float*)d_in[3];
    const float* at_s1 = (const float*)d_in[4];
    const float* at_d1 = (const float*)d_in[5];
    const float* b1    = (const float*)d_in[6];
    const float* W2    = (const float*)d_in[7];
    const float* at_s2 = (const float*)d_in[8];
    const float* at_d2 = (const float*)d_in[9];
    const float* b2    = (const float*)d_in[10];
    float* out = (float*)d_out;

    const int* src = ei;
    const int* dst = ei + NE;

    // workspace layout; g2 aliases h1 (h1 dead after k_msg1)
    char* w = (char*)d_ws;
    float* h1 = (float*)w;            w += (size_t)NN * 128 * 4;
    float* h2 = (float*)w;            w += (size_t)NN * 128 * 4;
    int2* packed = (int2*)w;          w += (size_t)NE * 8;
    float* as1 = (float*)w;           w += (size_t)NN * 4 * 4;
    float* ad1 = (float*)w;           w += (size_t)NN * 4 * 4;
    float* as2 = (float*)w;           w += (size_t)NN * 4;
    float* ad2 = (float*)w;           w += (size_t)NN * 4;
    int* deg = (int*)w;               w += (size_t)NN * 4;
    int* cursor = (int*)w;            w += (size_t)NN * 4;
    int* row_ptr = (int*)w;           w += (size_t)(NN + 1) * 4;
    int* bsum = (int*)w;              w += 512 * 4;
    float* g2 = h1;                   // alias

    // CSR build (rebuilt every call; ws is re-poisoned by harness)
    k_init<<<NBLK_SCAN, 256, 0, stream>>>(deg, cursor);
    k_deg<<<3125, 256, 0, stream>>>(dst, deg);
    k_scan1<<<NBLK_SCAN, 256, 0, stream>>>(deg, row_ptr, bsum);
    k_scan2<<<1, 512, 0, stream>>>(bsum);
    k_scan3<<<NBLK_SCAN, 256, 0, stream>>>(row_ptr, bsum);
    k_fill<<<3125, 256, 0, stream>>>(src, dst, ew, row_ptr, cursor, packed);

    // layer 1
    k_gemm1<<<dim3(1563, 2), 256, 0, stream>>>(x, W1, at_s1, at_d1, h1, as1, ad1);
    k_msg1<<<25000, 256, 0, stream>>>(row_ptr, packed, as1, ad1, h1, b1, h2);

    // layer 2
    k_gemm2<<<1563, 256, 0, stream>>>(h2, W2, at_s2, at_d2, g2, as2, ad2);
    k_msg2<<<25000, 256, 0, stream>>>(row_ptr, packed, as2, ad2, g2, b2, out);
}